// Round 9
// baseline (158.678 us; speedup 1.0000x reference)
//
#include <hip/hip_runtime.h>
#include <hip/hip_bf16.h>

#define N_NODES 100000
#define N_EDGES 3200000
#define IN_F 256
#define OUT_F 128

typedef __attribute__((ext_vector_type(8))) short bf16x8;
typedef __attribute__((ext_vector_type(4))) float f32x4;
typedef __attribute__((ext_vector_type(2))) unsigned int u32x2;

__device__ __forceinline__ unsigned short f2bf(float f) {
    unsigned int u = __float_as_uint(f);
    u += 0x7fffu + ((u >> 16) & 1u);   // round-to-nearest-even
    return (unsigned short)(u >> 16);
}

__device__ __forceinline__ short cvt_bf16(float f) {
    __hip_bfloat16 b = (__hip_bfloat16)f;      // native cvt (pairs -> v_cvt_pk_bf16_f32)
    return *reinterpret_cast<short*>(&b);
}

// byte k of x -> float (LLVM combines zext(trunc)+uitofp -> v_cvt_f32_ubyte_k)
#if __has_builtin(__builtin_amdgcn_cvt_f32_ubyte0)
#define UB0(x) __builtin_amdgcn_cvt_f32_ubyte0(x)
#define UB1(x) __builtin_amdgcn_cvt_f32_ubyte1(x)
#define UB2(x) __builtin_amdgcn_cvt_f32_ubyte2(x)
#define UB3(x) __builtin_amdgcn_cvt_f32_ubyte3(x)
#else
#define UB0(x) ((float)((unsigned char)((x))))
#define UB1(x) ((float)((unsigned char)((x) >> 8)))
#define UB2(x) ((float)((unsigned char)((x) >> 16)))
#define UB3(x) ((float)((x) >> 24))
#endif

// ---- Kernel 0: fused init: Wt transpose+convert AND CSR row_ptr ----
__global__ void k_init(const float* __restrict__ W, unsigned short* __restrict__ Wt,
                       const int* __restrict__ erow, int* __restrict__ row_ptr) {
    int e = blockIdx.x * 256 + threadIdx.x;
    if (e < IN_F * OUT_F) {            // W [256][128] f32 -> Wt [128][256] bf16
        int k = e >> 7;
        int c = e & 127;
        Wt[c * IN_F + k] = f2bf(W[e]);
    }
    if (e >= N_EDGES) return;
    int r = erow[e];
    int rprev = (e == 0) ? -1 : erow[e - 1];
    for (int rr = rprev + 1; rr <= r; ++rr) row_ptr[rr] = e;
    if (e == N_EDGES - 1) {
        for (int rr = r + 1; rr <= N_NODES; ++rr) row_ptr[rr] = N_EDGES;
    }
}

// ---- Kernel 2: H8u = biased-uint8 quant of tanh(A @ W). 128x128 tile.
//      A-loads software-pipelined one k-step ahead. Fast tanh via __expf.
//      store = round(clamp(h*qs, -127, 127)) + 128. ----
__global__ __launch_bounds__(256) void k_gemm(const float* __restrict__ A,
                                              const unsigned short* __restrict__ Wt,
                                              unsigned char* __restrict__ H8,
                                              const int* __restrict__ activep) {
    const int tid  = threadIdx.x;
    const int lane = tid & 63;
    const int wid  = tid >> 6;
    const int wr   = wid >> 1;   // 0..1 row-half
    const int wc   = wid & 1;    // 0..1 col-half
    const int brow = blockIdx.x * 128;
    const int l15  = lane & 15;
    const int lk   = (lane >> 4) * 8;  // k-offset of this lane's 8 elems

    // per-row A base pointers (constant over k)
    const float* ap[4];
    #pragma unroll
    for (int i = 0; i < 4; ++i) {
        int row = brow + wr * 64 + i * 16 + l15;
        if (row > N_NODES - 1) row = N_NODES - 1;   // clamp OOB reads
        ap[i] = A + (long)row * IN_F + lk;
    }
    // B base: b[n] = bp + n*16*IN_F + k0
    const unsigned short* bp = Wt + (long)(wc * 64 + l15) * IN_F + lk;

    f32x4 acc[4][4] = {};

    // prologue: raw A loads for k0 = 0
    float4 f0[4], f1[4];
    #pragma unroll
    for (int i = 0; i < 4; ++i) {
        f0[i] = *(const float4*)(ap[i]);
        f1[i] = *(const float4*)(ap[i] + 4);
    }

    for (int k0 = 0; k0 < IN_F; k0 += 32) {
        const int kn = k0 + 32;
        // issue next k-step's A loads first (pipeline)
        float4 n0[4], n1[4];
        if (kn < IN_F) {
            #pragma unroll
            for (int i = 0; i < 4; ++i) {
                n0[i] = *(const float4*)(ap[i] + kn);
                n1[i] = *(const float4*)(ap[i] + kn + 4);
            }
        }
        // convert current A to bf16 frags (native cvt, packs to cvt_pk)
        bf16x8 a[4];
        #pragma unroll
        for (int i = 0; i < 4; ++i) {
            bf16x8 v;
            v[0] = cvt_bf16(f0[i].x); v[1] = cvt_bf16(f0[i].y);
            v[2] = cvt_bf16(f0[i].z); v[3] = cvt_bf16(f0[i].w);
            v[4] = cvt_bf16(f1[i].x); v[5] = cvt_bf16(f1[i].y);
            v[6] = cvt_bf16(f1[i].z); v[7] = cvt_bf16(f1[i].w);
            a[i] = v;
        }
        // B frags (Wt is L2/L3-resident)
        bf16x8 b[4];
        #pragma unroll
        for (int n = 0; n < 4; ++n)
            b[n] = *(const bf16x8*)(bp + (long)n * 16 * IN_F + k0);

        #pragma unroll
        for (int i = 0; i < 4; ++i)
            #pragma unroll
            for (int n = 0; n < 4; ++n)
                acc[i][n] = __builtin_amdgcn_mfma_f32_16x16x32_bf16(a[i], b[n], acc[i][n], 0, 0, 0);

        if (kn < IN_F) {
            #pragma unroll
            for (int i = 0; i < 4; ++i) { f0[i] = n0[i]; f1[i] = n1[i]; }
        }
    }

    const int act = *activep;
    const float qs = act ? 127.0f : 16.0f;
    // C/D layout: col = lane&15, row = (lane>>4)*4 + reg   [m89-verified]
    #pragma unroll
    for (int i = 0; i < 4; ++i) {
        #pragma unroll
        for (int n = 0; n < 4; ++n) {
            #pragma unroll
            for (int r = 0; r < 4; ++r) {
                int row = brow + wr * 64 + i * 16 + (lane >> 4) * 4 + r;
                int col = wc * 64 + n * 16 + l15;
                if (row < N_NODES) {
                    float v = acc[i][n][r];
                    if (act) {
                        // tanh(v) = 1 - 2/(e^{2v}+1)
                        float t = __expf(2.0f * v);
                        v = 1.0f - __fdividef(2.0f, t + 1.0f);
                    }
                    float q = v * qs;
                    q = fminf(fmaxf(q, -127.0f), 127.0f);
                    H8[(long)row * OUT_F + col] =
                        (unsigned char)(__float2int_rn(q) + 128);
                }
            }
        }
    }
}

// ---- Kernel 3: SpMM over biased-uint8 h (128B rows). One wave per row;
//      32 edges/iter. 16 lanes x 8B cover one edge's row; slot q handles
//      edges j+u*4+q, u=0..7 -> 8 asm-forced global_load_dwordx2 gathers
//      (4KB/wave in flight). Clamped edge index so dead gathers coalesce.
//      Unpack: cvt_f32_ubyte + fma (2 ops/col); bias folds via vs=sum(v):
//      out = sum(v*u) - 128*sum(v). shfl_xor(16/32) butterfly at end. ----
__global__ __launch_bounds__(256) void k_spmm(const int* __restrict__ row_ptr,
                                              const int* __restrict__ ecol,
                                              const float* __restrict__ eval,
                                              const unsigned char* __restrict__ h8,
                                              const int* __restrict__ activep,
                                              float* __restrict__ out) {
    const int lane = threadIdx.x & 63;
    const int w    = threadIdx.x >> 6;
    const int r    = blockIdx.x * 4 + w;
    if (r >= N_NODES) return;

    const int q   = lane >> 4;        // edge slot 0..3
    const int l15 = lane & 15;
    const unsigned dqb = (unsigned)l15 * 8u;   // byte offset within 128B h row

    const int s = __builtin_amdgcn_readfirstlane(row_ptr[r]);
    const int e = __builtin_amdgcn_readfirstlane(row_ptr[r + 1]);
    const int act = __builtin_amdgcn_readfirstlane(*activep);
    const float invs = act ? (1.0f / 127.0f) : (1.0f / 16.0f);

    float f0 = 0.f, f1 = 0.f, f2 = 0.f, f3 = 0.f;
    float f4 = 0.f, f5 = 0.f, f6 = 0.f, f7 = 0.f;
    float vs = 0.f;

    for (int j = s; j < e; j += 32) {
        int   cc[8];
        float vv[8];
        #pragma unroll
        for (int u = 0; u < 8; ++u) {
            const int want = j + u * 4 + q;
            const int idx  = min(want, e - 1);     // in-bounds; dead lanes coalesce
            cc[u] = ecol[idx];
            vv[u] = (want < e) ? eval[idx] * invs : 0.f;
        }
        const unsigned o0 = dqb + (((unsigned)cc[0]) << 7);
        const unsigned o1 = dqb + (((unsigned)cc[1]) << 7);
        const unsigned o2 = dqb + (((unsigned)cc[2]) << 7);
        const unsigned o3 = dqb + (((unsigned)cc[3]) << 7);
        const unsigned o4 = dqb + (((unsigned)cc[4]) << 7);
        const unsigned o5 = dqb + (((unsigned)cc[5]) << 7);
        const unsigned o6 = dqb + (((unsigned)cc[6]) << 7);
        const unsigned o7 = dqb + (((unsigned)cc[7]) << 7);

        u32x2 g0, g1, g2, g3, g4, g5, g6, g7;
        asm volatile("global_load_dwordx2 %0, %1, %2" : "=v"(g0) : "v"(o0), "s"(h8));
        asm volatile("global_load_dwordx2 %0, %1, %2" : "=v"(g1) : "v"(o1), "s"(h8));
        asm volatile("global_load_dwordx2 %0, %1, %2" : "=v"(g2) : "v"(o2), "s"(h8));
        asm volatile("global_load_dwordx2 %0, %1, %2" : "=v"(g3) : "v"(o3), "s"(h8));
        asm volatile("global_load_dwordx2 %0, %1, %2" : "=v"(g4) : "v"(o4), "s"(h8));
        asm volatile("global_load_dwordx2 %0, %1, %2" : "=v"(g5) : "v"(o5), "s"(h8));
        asm volatile("global_load_dwordx2 %0, %1, %2" : "=v"(g6) : "v"(o6), "s"(h8));
        asm volatile("global_load_dwordx2 %0, %1, %2" : "=v"(g7) : "v"(o7), "s"(h8));
        asm volatile("s_waitcnt vmcnt(0)" ::: "memory");
        __builtin_amdgcn_sched_barrier(0);

        #define EDGE_FMA(G, V)                      \
            do {                                    \
                const float v_ = (V);               \
                vs += v_;                           \
                const unsigned x_ = (G).x, y_ = (G).y; \
                f0 = fmaf(v_, UB0(x_), f0);         \
                f1 = fmaf(v_, UB1(x_), f1);         \
                f2 = fmaf(v_, UB2(x_), f2);         \
                f3 = fmaf(v_, UB3(x_), f3);         \
                f4 = fmaf(v_, UB0(y_), f4);         \
                f5 = fmaf(v_, UB1(y_), f5);         \
                f6 = fmaf(v_, UB2(y_), f6);         \
                f7 = fmaf(v_, UB3(y_), f7);         \
            } while (0)
        EDGE_FMA(g0, vv[0]); EDGE_FMA(g1, vv[1]); EDGE_FMA(g2, vv[2]); EDGE_FMA(g3, vv[3]);
        EDGE_FMA(g4, vv[4]); EDGE_FMA(g5, vv[5]); EDGE_FMA(g6, vv[6]); EDGE_FMA(g7, vv[7]);
        #undef EDGE_FMA
    }

    // remove the +128 bias: out = sum(v*u) - 128*sum(v)   (per-lane, linear)
    const float bias = 128.0f * vs;
    f0 -= bias; f1 -= bias; f2 -= bias; f3 -= bias;
    f4 -= bias; f5 -= bias; f6 -= bias; f7 -= bias;

    // reduce the 4 edge slots: lanes l, l+16, l+32, l+48 hold the same columns
    #pragma unroll
    for (int mask = 16; mask <= 32; mask <<= 1) {
        f0 += __shfl_xor(f0, mask);
        f1 += __shfl_xor(f1, mask);
        f2 += __shfl_xor(f2, mask);
        f3 += __shfl_xor(f3, mask);
        f4 += __shfl_xor(f4, mask);
        f5 += __shfl_xor(f5, mask);
        f6 += __shfl_xor(f6, mask);
        f7 += __shfl_xor(f7, mask);
    }

    if (q == 0) {
        float* dst = out + (long)r * OUT_F + l15 * 8;
        float4 o0v; o0v.x = f0; o0v.y = f1; o0v.z = f2; o0v.w = f3;
        float4 o1v; o1v.x = f4; o1v.y = f5; o1v.z = f6; o1v.w = f7;
        *(float4*)dst       = o0v;
        *(float4*)(dst + 4) = o1v;
    }
}

extern "C" void kernel_launch(void* const* d_in, const int* in_sizes, int n_in,
                              void* d_out, int out_size, void* d_ws, size_t ws_size,
                              hipStream_t stream) {
    const float* features = (const float*)d_in[0];
    const float* weight   = (const float*)d_in[1];
    const int*   erow     = (const int*)d_in[2];
    const int*   ecol     = (const int*)d_in[3];
    const float* evalp    = (const float*)d_in[4];
    const int*   activep  = (const int*)d_in[5];
    float* out = (float*)d_out;

    char* ws = (char*)d_ws;
    unsigned char* H8  = (unsigned char*)ws;                          // 12,800,000 B
    unsigned short* Wt = (unsigned short*)(ws + 12800000);            //     65,536 B
    int* row_ptr       = (int*)(ws + 12800000 + 65536);               //    400,004 B

    k_init  <<<(N_EDGES + 255) / 256, 256, 0, stream>>>(weight, Wt, erow, row_ptr);
    k_gemm  <<<(N_NODES + 127) / 128, 256, 0, stream>>>(features, Wt, H8, activep);
    k_spmm  <<<(N_NODES + 3) / 4, 256, 0, stream>>>(row_ptr, ecol, evalp,
                                                    H8, activep, out);
}